// Round 5
// baseline (166.662 us; speedup 1.0000x reference)
//
#include <hip/hip_runtime.h>
#include <hip/hip_bf16.h>

// Problem constants
#define CO    128
#define CI    128
#define NPIX  3136   // 56*56
#define PH    58
#define PPIX  3364   // 58*58
#define HPX   232    // halo pixels per block: 4 padded rows * 58
#define SROW  272    // LDS bytes per halo pixel: 256 data + 16 pad

typedef __bf16 bf16x8 __attribute__((ext_vector_type(8)));
typedef float  f32x4  __attribute__((ext_vector_type(4)));

// ---------------------------------------------------------------------------
// Fused prep: [0,2048) weights | [2048,2504) border zero | [2504,4072) transpose.
// ---------------------------------------------------------------------------
__global__ void prep_all(const float* __restrict__ in,
                         const float* __restrict__ eps,
                         const float* __restrict__ psi,
                         const float* __restrict__ mu,
                         __bf16* __restrict__ wt,
                         __bf16* __restrict__ it) {
  __shared__ __align__(16) __bf16 T[64][136];
  const int bx = blockIdx.x, tid = threadIdx.x;

  if (bx < 2048) {
    int idx = bx * 256 + tid;               // = (b*CO+co)*CI+ci
    int ci = idx & 127;
    int co = (idx >> 7) & 127;
    const float* e  = eps + (size_t)idx * 9;
    const float* ps = psi + (size_t)(co * CI + ci) * 9;
    const float* m  = mu  + (size_t)(co * CI + ci) * 9;
    float v[9];
#pragma unroll
    for (int p = 0; p < 9; ++p) v[p] = e[p] * __expf(ps[p]) + m[p];
    int b = idx >> 14;
    __bf16* w = wt + ((size_t)b * 9 * CO + co) * CI + ci;
#pragma unroll
    for (int p = 0; p < 9; ++p) w[(size_t)p * CO * CI] = (__bf16)v[p];
  } else if (bx < 2504) {
    int cid = (bx - 2048) * 256 + tid;
    int pid = cid >> 4;
    int chunk = cid & 15;
    int b = pid / 228;
    int e = pid - b * 228;
    int ph, pw;
    if (e < 58)       { ph = 0;       pw = e; }
    else if (e < 116) { ph = 57;      pw = e - 58; }
    else if (e < 172) { ph = e - 115; pw = 0; }
    else              { ph = e - 171; pw = 57; }
    f32x4 z = {0.f, 0.f, 0.f, 0.f};
    *(f32x4*)&it[((size_t)b * PPIX + ph * PH + pw) * CI + chunk * 8] = z;
  } else {
    int tx = bx - 2504;
    int b  = tx / 49;
    int p0 = (tx - b * 49) * 64;
    const float* src = in + (size_t)b * CI * NPIX;
#pragma unroll
    for (int jj = 0; jj < 8; ++jj) {
      int c = jj * 256 + tid;
      int ci = c >> 4, xc = c & 15;
      float4 v = *(const float4*)(src + (size_t)ci * NPIX + p0 + xc * 4);
      T[xc * 4 + 0][ci] = (__bf16)v.x;
      T[xc * 4 + 1][ci] = (__bf16)v.y;
      T[xc * 4 + 2][ci] = (__bf16)v.z;
      T[xc * 4 + 3][ci] = (__bf16)v.w;
    }
    __syncthreads();
    __bf16* dstb = it + (size_t)b * PPIX * CI;
#pragma unroll
    for (int jj = 0; jj < 4; ++jj) {
      int c = jj * 256 + tid;
      int pl = c >> 4, xc = c & 15;
      int pix = p0 + pl;
      int oh = pix / 56, ow = pix - oh * 56;
      int ppix = (oh + 1) * PH + (ow + 1);
      *(f32x4*)&dstb[(size_t)ppix * CI + xc * 8] = *(const f32x4*)&T[pl][xc * 8];
    }
  }
}

// ---------------------------------------------------------------------------
// Conv GEMM, barrier-free halo K-loop, v2:
//   block = 128 threads = 2 waves; wave w = 64co x 112n (4x7 frags).
//   Each B-frag from LDS feeds 4 MFMAs (vs 2 in R4) -> LDS traffic halved.
//   Explicit even/odd register double-buffer on BOTH A (global) and B (LDS):
//   loads for step s+1 issue before MFMAs of step s. No barrier after prologue.
//   Grid 896 = 28 row-pair tiles x 32 batch, XCD swizzle (lin%8 = b%8).
// ---------------------------------------------------------------------------
__device__ __forceinline__ void loadB(const char* Bsh, const int* bbase, int tapb,
                                      bf16x8 bf[7]) {
#pragma unroll
  for (int nf = 0; nf < 7; ++nf)
    bf[nf] = *(const bf16x8*)&Bsh[bbase[nf] + tapb];
}

__device__ __forceinline__ void loadA(const __bf16* wtb, const int* ab, int s,
                                      bf16x8 af[4]) {
  const int p   = s >> 2;
  const int ci0 = (s & 3) << 5;
  const __bf16* ap = wtb + p * (CO * CI) + ci0;
#pragma unroll
  for (int mf = 0; mf < 4; ++mf)
    af[mf] = *(const bf16x8*)(ap + ab[mf]);
}

__device__ __forceinline__ void do_mfma(const bf16x8 af[4], const bf16x8 bf[7],
                                        f32x4 acc[4][7]) {
#pragma unroll
  for (int mf = 0; mf < 4; ++mf)
#pragma unroll
    for (int nf = 0; nf < 7; ++nf)
      acc[mf][nf] = __builtin_amdgcn_mfma_f32_16x16x32_bf16(
          af[mf], bf[nf], acc[mf][nf], 0, 0, 0);
}

#define TAPB(s) ((((s) >> 2) / 3) * PH + (((s) >> 2) % 3)) * SROW + (((s) & 3) << 6)

__global__ __launch_bounds__(128, 1) void bconv_gemm(
    const __bf16* __restrict__ wt,   // [b][9][128 co][128 ci]
    const __bf16* __restrict__ it,   // [b][3364 pix][128 ci]
    float* __restrict__ out) {       // [b][128 co][3136 n]
  __shared__ __align__(16) char Bsh[HPX * SROW];   // 63104 B
  const int tid  = threadIdx.x;
  const int w    = tid >> 6;
  const int lane = tid & 63;
  const int quad = lane >> 4;
  const int l15  = lane & 15;

  // Decode: lin = x + 8*(tile*4 + bhi); b = x + 8*bhi
  const int lin = blockIdx.x;
  const int x   = lin & 7;
  const int j   = lin >> 3;          // 0..111
  const int bhi = j & 3;
  const int tile = j >> 2;           // 0..27
  const int b   = x + 8 * bhi;
  const int oh0 = tile * 2;

  // ---- prologue: stage 4-padded-row halo (contiguous in it[]) ----
  const __bf16* hsrc = it + ((size_t)b * PPIX + oh0 * PH) * CI;
#pragma unroll
  for (int i = 0; i < 29; ++i) {               // 29*128 = 3712 chunks exactly
    int idx = i * 128 + tid;
    int px = idx >> 4, sub = idx & 15;
    f32x4 v = *(const f32x4*)(hsrc + (size_t)idx * 8);
    *(f32x4*)&Bsh[px * SROW + sub * 16] = v;
  }
  __syncthreads();

  // ---- per-lane B fragment LDS byte-bases (tap (0,0), ci-slice 0) ----
  int bbase[7];
#pragma unroll
  for (int nf = 0; nf < 7; ++nf) {
    int n = nf * 16 + l15;                     // 0..111
    int r = (n >= 56) ? 1 : 0;
    bbase[nf] = (n + 2 * r) * SROW + quad * 16;
  }

  // ---- per-lane A element bases: rows co0+{0,16,32,48}+l15, k = quad*8 ----
  const int co0 = w * 64;
  const __bf16* wtb = wt + (size_t)b * 9 * CO * CI;
  int ab[4];
#pragma unroll
  for (int mf = 0; mf < 4; ++mf)
    ab[mf] = (co0 + mf * 16 + l15) * CI + quad * 8;

  f32x4 acc[4][7] = {};
  bf16x8 a0[4], a1[4], b0[7], b1[7];

  loadA(wtb, ab, 0, a0);
  loadB(Bsh, bbase, TAPB(0), b0);
#pragma unroll
  for (int s = 0; s < 34; s += 2) {
    loadA(wtb, ab, s + 1, a1);
    loadB(Bsh, bbase, TAPB(s + 1), b1);
    do_mfma(a0, b0, acc);
    loadA(wtb, ab, s + 2, a0);
    loadB(Bsh, bbase, TAPB(s + 2), b0);
    do_mfma(a1, b1, acc);
  }
  loadA(wtb, ab, 35, a1);
  loadB(Bsh, bbase, TAPB(35), b1);
  do_mfma(a0, b0, acc);
  do_mfma(a1, b1, acc);

  // ---- epilogue: C col(l15)=n, row(quad*4+r)=co ----
  float* ob = out + (size_t)b * CO * NPIX + oh0 * 56;
#pragma unroll
  for (int mf = 0; mf < 4; ++mf) {
#pragma unroll
    for (int nf = 0; nf < 7; ++nf) {
#pragma unroll
      for (int r = 0; r < 4; ++r) {
        int co = co0 + mf * 16 + quad * 4 + r;
        ob[(size_t)co * NPIX + nf * 16 + l15] = acc[mf][nf][r];
      }
    }
  }
}

// ---------------------------------------------------------------------------
extern "C" void kernel_launch(void* const* d_in, const int* in_sizes, int n_in,
                              void* d_out, int out_size, void* d_ws, size_t ws_size,
                              hipStream_t stream) {
  const float* inp = (const float*)d_in[0];   // [32,128,56,56]
  const float* eps = (const float*)d_in[1];   // [32,128,128,3,3]
  const float* psi = (const float*)d_in[2];   // [128,128,3,3]
  const float* mu  = (const float*)d_in[3];   // [128,128,3,3]

  // ws layout: wt (9,437,184 B) | inp_t (27,557,888 B)
  __bf16* wt = (__bf16*)d_ws;
  __bf16* it = (__bf16*)((char*)d_ws + 9437184);

  prep_all<<<4072, 256, 0, stream>>>(inp, eps, psi, mu, wt, it);
  bconv_gemm<<<896, 128, 0, stream>>>(wt, it, (float*)d_out);
}